// Round 2
// baseline (815.164 us; speedup 1.0000x reference)
//
#include <hip/hip_runtime.h>

#define D 128
#define BD (D * D) // 16384

typedef float v4f __attribute__((ext_vector_type(4)));

// ---------------- Kernel 1: normalize rows + per-row scalars ----------------
__global__ __launch_bounds__(128) void prep_kernel(
    const float* __restrict__ z1, const float* __restrict__ z2,
    float* __restrict__ u1n, float* __restrict__ u2n,
    float* __restrict__ scal) {
    const int b = blockIdx.x;
    const int t = threadIdx.x; // 0..127

    const float v1 = z1[(size_t)b * D + t];
    const float v2 = z2[(size_t)b * D + t];
    float s1 = v1 * v1, s2 = v2 * v2, s12 = v1 * v2;
#pragma unroll
    for (int off = 32; off > 0; off >>= 1) {
        s1  += __shfl_down(s1, off, 64);
        s2  += __shfl_down(s2, off, 64);
        s12 += __shfl_down(s12, off, 64);
    }
    __shared__ float w1[2], w2[2], w12[2];
    const int wave = t >> 6, lane = t & 63;
    if (lane == 0) { w1[wave] = s1; w2[wave] = s2; w12[wave] = s12; }
    __syncthreads();

    const float n1sq = w1[0] + w1[1];
    const float n2sq = w2[0] + w2[1];
    const float dot  = w12[0] + w12[1];
    const float n1 = sqrtf(n1sq), n2 = sqrtf(n2sq);

    u1n[(size_t)b * D + t] = v1 / n1;
    u2n[(size_t)b * D + t] = v2 / n2;
    if (t == 0) {
        const float inv12 = 1.0f / (n1 * n2);
        v4f s;
        s[0] = dot * inv12;   // c
        s[1] = 1.0f / n1sq;   // inv11
        s[2] = inv12;         // inv12
        s[3] = 1.0f / n2sq;   // inv22
        *(v4f*)(scal + b * 4) = s;
    }
}

// ---------------- Kernel 2: fill-identical dense sweep writer ----------------
// Total v4f elements: 3 * 4096 * 16384 / 4 = 50,331,648 = 3 * 2^24.
// Thread tid writes s = tid + it*524288 — the same dense forward window sweep
// the 6.3 TB/s fillBuffer kernel uses. All operand data (4 MB) is L2-resident.
__global__ __launch_bounds__(256) void sweep_kernel(
    const float* __restrict__ u1n, const float* __restrict__ u2n,
    const float* __restrict__ scal, float* __restrict__ out) {
    const unsigned tid = blockIdx.x * 256u + threadIdx.x; // 0..524287
    v4f* o = (v4f*)out;

#pragma unroll 2
    for (int it = 0; it < 96; ++it) {
        const unsigned s  = tid + (unsigned)it * 524288u;
        const unsigned p  = s >> 24;          // plane 0..2
        const unsigned r  = s & 0xFFFFFFu;    // v4f index within plane
        const unsigned b  = r >> 12;          // 4096 v4f per matrix
        const unsigned e  = r & 0xFFFu;       // v4f index within matrix
        const unsigned i  = e >> 5;           // row (32 v4f per 128-col row)
        const unsigned j0 = (e & 31u) << 2;   // first column of the v4f

        const float* u1b = u1n + ((size_t)b << 7);
        const float* u2b = u2n + ((size_t)b << 7);
        const float a1 = u1b[i];
        const float a2 = u2b[i];
        const v4f bj1 = *(const v4f*)(u1b + j0);
        const v4f bj2 = *(const v4f*)(u2b + j0);
        const v4f sc  = *(const v4f*)(scal + (b << 2));
        const float c = sc[0];

        v4f h;
        if (p == 0) {
            const float m = sc[1], c3 = 3.0f * c;
#pragma unroll
            for (int q = 0; q < 4; ++q) {
                const float o11 = a1 * bj1[q];
                const float o12 = a1 * bj2[q];
                const float o21 = a2 * bj1[q];
                const float dg  = (j0 + q == i) ? c : 0.0f;
                h[q] = (o12 + o21 - c3 * o11 + dg) * m;
            }
        } else if (p == 1) {
            const float m = sc[2];
#pragma unroll
            for (int q = 0; q < 4; ++q) {
                const float o11 = a1 * bj1[q];
                const float o21 = a2 * bj1[q];
                const float o22 = a2 * bj2[q];
                const float dg  = (j0 + q == i) ? 1.0f : 0.0f;
                h[q] = (o11 + o22 - c * o21 - dg) * m;
            }
        } else {
            const float m = sc[3], c3 = 3.0f * c;
#pragma unroll
            for (int q = 0; q < 4; ++q) {
                const float o12 = a1 * bj2[q];
                const float o21 = a2 * bj1[q];
                const float o22 = a2 * bj2[q];
                const float dg  = (j0 + q == i) ? c : 0.0f;
                h[q] = (o12 + o21 - c3 * o22 + dg) * m;
            }
        }
        o[s] = h;
    }
}

// ---------------- Fallback: previous single-kernel version ----------------
__global__ __launch_bounds__(256) void arccos_hess_kernel(
    const float* __restrict__ z1, const float* __restrict__ z2,
    float* __restrict__ out, int B) {
    const int b = blockIdx.x;
    const int t = threadIdx.x;

    __shared__ float u1[D], u2[D];
    __shared__ float ws1[4], ws2[4], ws12[4];

    float v1 = 0.f, v2 = 0.f;
    if (t < D) {
        v1 = z1[(size_t)b * D + t];
        v2 = z2[(size_t)b * D + t];
    }
    float s1 = v1 * v1, s2 = v2 * v2, s12 = v1 * v2;
#pragma unroll
    for (int off = 32; off > 0; off >>= 1) {
        s1  += __shfl_down(s1, off, 64);
        s2  += __shfl_down(s2, off, 64);
        s12 += __shfl_down(s12, off, 64);
    }
    const int wave = t >> 6, lane = t & 63;
    if (lane == 0) { ws1[wave] = s1; ws2[wave] = s2; ws12[wave] = s12; }
    __syncthreads();

    const float n1sq = ws1[0] + ws1[1] + ws1[2] + ws1[3];
    const float n2sq = ws2[0] + ws2[1] + ws2[2] + ws2[3];
    const float dot  = ws12[0] + ws12[1] + ws12[2] + ws12[3];
    const float n1 = sqrtf(n1sq), n2 = sqrtf(n2sq);
    const float inv11 = 1.0f / n1sq;
    const float inv22 = 1.0f / n2sq;
    const float inv12 = 1.0f / (n1 * n2);
    const float c  = dot * inv12;
    const float c3 = 3.0f * c;

    if (t < D) {
        u1[t] = v1 / n1;
        u2[t] = v2 / n2;
    }
    __syncthreads();

    const int j0 = (t & 31) << 2;
    const float uj1[4] = { u1[j0], u1[j0 + 1], u1[j0 + 2], u1[j0 + 3] };
    const float uj2[4] = { u2[j0], u2[j0 + 1], u2[j0 + 2], u2[j0 + 3] };

    float* out0 = out + (size_t)b * BD;
    float* out1 = out0 + (size_t)B * BD;
    float* out2 = out1 + (size_t)B * BD;

#pragma unroll
    for (int k = 0; k < 16; ++k) {
        const int i = (t >> 5) + (k << 3);
        const float a1 = u1[i];
        const float a2 = u2[i];

        v4f h11, h12, h22;
#pragma unroll
        for (int q = 0; q < 4; ++q) {
            const float b1 = uj1[q], b2 = uj2[q];
            const float o11 = a1 * b1;
            const float o12 = a1 * b2;
            const float o21 = a2 * b1;
            const float o22 = a2 * b2;
            const float s1221 = o12 + o21;
            const float diag = (i == j0 + q) ? 1.0f : 0.0f;
            h11[q] = (s1221 - c3 * o11 + c * diag) * inv11;
            h12[q] = (o11 + o22 - c * o21 - diag) * inv12;
            h22[q] = (s1221 - c3 * o22 + c * diag) * inv22;
        }
        const size_t off = (size_t)i * D + j0;
        *(v4f*)(out0 + off) = h11;
        *(v4f*)(out1 + off) = h12;
        *(v4f*)(out2 + off) = h22;
    }
}

extern "C" void kernel_launch(void* const* d_in, const int* in_sizes, int n_in,
                              void* d_out, int out_size, void* d_ws, size_t ws_size,
                              hipStream_t stream) {
    const float* z1 = (const float*)d_in[0];
    const float* z2 = (const float*)d_in[1];
    float* out = (float*)d_out;
    const int B = in_sizes[0] / D;

    const size_t need = (size_t)2 * 4096 * 128 * 4 + 4096 * 4 * 4; // 4.26 MB
    if (B == 4096 && ws_size >= need) {
        float* u1n  = (float*)d_ws;
        float* u2n  = u1n + (size_t)4096 * 128;
        float* scal = u2n + (size_t)4096 * 128;
        prep_kernel<<<4096, 128, 0, stream>>>(z1, z2, u1n, u2n, scal);
        sweep_kernel<<<2048, 256, 0, stream>>>(u1n, u2n, scal, out);
    } else {
        arccos_hess_kernel<<<B, 256, 0, stream>>>(z1, z2, out, B);
    }
}